// Round 10
// baseline (165.460 us; speedup 1.0000x reference)
//
#include <hip/hip_runtime.h>
#include <hip/hip_fp16.h>
#include <stdint.h>

// Problem constants: Xp(16384,3) X(8192,3) W(64,8192) eps scalar -> out(16384,64)
#define M_ROWS 16384
#define N_PTS  8192
#define K_OUT  64

typedef _Float16       h2    __attribute__((ext_vector_type(2)));
typedef unsigned short u16x2 __attribute__((ext_vector_type(2)));
typedef _Float16       f16x8 __attribute__((ext_vector_type(8)));
typedef float          f32x4 __attribute__((ext_vector_type(4)));

union AF { f16x8 v; uint4 q; uint32_t u[4]; h2 h[4]; };

__device__ __forceinline__ h2 pkrtz2(float a, float b) {
    return __builtin_bit_cast(h2, __builtin_amdgcn_cvt_pkrtz(a, b));
}
__device__ __forceinline__ uint32_t pkrtz(float a, float b) {
    return __builtin_bit_cast(uint32_t, __builtin_amdgcn_cvt_pkrtz(a, b));
}

// packed fast sqrt(t), t in [1, ~512]: per-half rsqrt bit-seed + 1 reassociated
// Newton. 6 packed VALU ops / 2 phis. Rel err <= ~3e-3 (validated r5-r9, absmax 8).
__device__ __forceinline__ h2 pk_sqrt_fast(h2 t, h2 mhf, h2 c15) {
    u16x2 u = __builtin_bit_cast(u16x2, t);
    u16x2 r0u = (u16x2){0x59BA, 0x59BA} - (u >> 1);
    h2 r0 = __builtin_bit_cast(h2, r0u);
    h2 y = t * r0;
    h2 p = y * r0;
    h2 k = __builtin_elementwise_fma(p, mhf, c15);
    return y * k;
}

// ---------------- prep (unchanged since r7) ----------------
__global__ __launch_bounds__(256) void rbf_prep(
    const float* __restrict__ Wf, const float* __restrict__ X,
    const float* __restrict__ epsp,
    uint4* __restrict__ Wt, uint32_t* __restrict__ Cx,
    uint32_t* __restrict__ Cy, uint32_t* __restrict__ Cz,
    uint32_t* __restrict__ Cc)
{
    const int bid = blockIdx.x, tid = threadIdx.x;
    if (bid < 256) {
        const int kt = tid >> 6, lane = tid & 63;
        const int l15 = lane & 15, g = lane >> 4;
        const int row = kt * 16 + l15;
        const int col = bid * 32 + g * 8;
        const float4* src = (const float4*)(Wf + row * N_PTS + col);
        const float4 w0 = src[0], w1 = src[1];
        uint4 p;
        p.x = pkrtz(w0.x, w0.y);
        p.y = pkrtz(w0.z, w0.w);
        p.z = pkrtz(w1.x, w1.y);
        p.w = pkrtz(w1.z, w1.w);
        Wt[(bid * 4 + kt) * 64 + lane] = p;
    } else {
        const int n = (bid - 256) * 256 + tid;       // pair index [0, 4096)
        const float e = *epsp;
        const float2 A = *(const float2*)(X + 6 * n);      // x0 y0
        const float2 B = *(const float2*)(X + 6 * n + 2);  // z0 x1
        const float2 C = *(const float2*)(X + 6 * n + 4);  // y1 z1
        const float x0 = A.x * e, y0 = A.y * e, z0 = B.x * e;
        const float x1 = B.y * e, y1 = C.x * e, z1 = C.y * e;
        Cx[n] = pkrtz(-2.0f * x0, -2.0f * x1);
        Cy[n] = pkrtz(-2.0f * y0, -2.0f * y1);
        Cz[n] = pkrtz(-2.0f * z0, -2.0f * z1);
        Cc[n] = pkrtz(fmaf(x0, x0, fmaf(y0, y0, fmaf(z0, z0, 1.0f))),
                      fmaf(x1, x1, fmaf(y1, y1, fmaf(z1, z1, 1.0f))));
    }
}

// ---------------- main: T=4 row-tiles/wave, 16 n-chunks/block ----------------
// 256 blocks x 1024 threads (1 block/CU, 4 waves/SIMD at 128-reg cap).
// Block owns rows [bid*64, bid*64+64); wave wv = n-chunk covers pts
// [wv*512,(wv+1)*512) = 16 iters of 32 pts. Each W fragment feeds 4 MFMAs
// (one per row-tile) -> half of r7's VMEM instruction count, 2x the ILP.
// Reg budget: acc 64 + W 16 + coords 16 + geom 16 + misc ~12 ≈ 108 <= 128.
// Partials: two-phase f16 merge into 8 slots (64 KB LDS, static-safe).
__global__ __launch_bounds__(1024, 4) void rbf_main(
    const float* __restrict__ Xp, const uint4* __restrict__ Wt,
    const uint32_t* __restrict__ Cx, const uint32_t* __restrict__ Cy,
    const uint32_t* __restrict__ Cz, const uint32_t* __restrict__ Cc,
    const float* __restrict__ epsp, float* __restrict__ out)
{
    __shared__ __align__(16) _Float16 sR[8 * 64 * 64];   // 64 KB: [slot][row(64)][col(64)]

    const int tid  = threadIdx.x;
    const int lane = tid & 63;
    const int wv   = tid >> 6;        // n-chunk 0..15
    const int m    = lane & 15;
    const int g    = lane >> 4;

    const int rowbase = blockIdx.x * 64;

    // per-lane row geometry for 4 tiles (rows rowbase + t*16 + m), f16 splat pairs
    const float e = *epsp;
    h2 pxk[4], pyk[4], pzk[4], aak[4];
    #pragma unroll
    for (int t = 0; t < 4; ++t) {
        const int r = rowbase + t * 16 + m;
        const float px = Xp[3 * r + 0] * e;
        const float py = Xp[3 * r + 1] * e;
        const float pz = Xp[3 * r + 2] * e;
        const float a  = fmaf(px, px, fmaf(py, py, pz * pz));
        pxk[t] = pkrtz2(px, px);
        pyk[t] = pkrtz2(py, py);
        pzk[t] = pkrtz2(pz, pz);
        aak[t] = pkrtz2(a, a);
    }
    const h2 mhf = {(_Float16)-0.5f, (_Float16)-0.5f};
    const h2 c15 = {(_Float16)1.5f, (_Float16)1.5f};

    f32x4 acc[4][4];
    #pragma unroll
    for (int t = 0; t < 4; ++t)
        #pragma unroll
        for (int kt = 0; kt < 4; ++kt)
            acc[t][kt] = (f32x4){0.f, 0.f, 0.f, 0.f};

    // uniform bases; divergent part is a FIXED lane offset
    const uint32_t* cxp = Cx + wv * 256 + g * 4;   // + s*16 dwords (imm <= 960 B)
    const uint32_t* cyp = Cy + wv * 256 + g * 4;
    const uint32_t* czp = Cz + wv * 256 + g * 4;
    const uint32_t* ccp = Cc + wv * 256 + g * 4;
    const uint4*    wp  = Wt + wv * 4096 + lane;   // + s*256 (SGPR) + kt*64 (imm)

    #pragma unroll 4
    for (int s = 0; s < 16; ++s) {
        const uint4 vx = *(const uint4*)(cxp + s * 16);
        const uint4 vy = *(const uint4*)(cyp + s * 16);
        const uint4 vz = *(const uint4*)(czp + s * 16);
        const uint4 vc = *(const uint4*)(ccp + s * 16);

        AF wf0, wf1, wf2, wf3;
        wf0.q = wp[s * 256];
        wf1.q = wp[s * 256 + 64];
        wf2.q = wp[s * 256 + 128];
        wf3.q = wp[s * 256 + 192];

        const h2 cx[4] = {__builtin_bit_cast(h2, vx.x), __builtin_bit_cast(h2, vx.y),
                          __builtin_bit_cast(h2, vx.z), __builtin_bit_cast(h2, vx.w)};
        const h2 cy[4] = {__builtin_bit_cast(h2, vy.x), __builtin_bit_cast(h2, vy.y),
                          __builtin_bit_cast(h2, vy.z), __builtin_bit_cast(h2, vy.w)};
        const h2 cz[4] = {__builtin_bit_cast(h2, vz.x), __builtin_bit_cast(h2, vz.y),
                          __builtin_bit_cast(h2, vz.z), __builtin_bit_cast(h2, vz.w)};
        const h2 cc[4] = {__builtin_bit_cast(h2, vc.x), __builtin_bit_cast(h2, vc.y),
                          __builtin_bit_cast(h2, vc.z), __builtin_bit_cast(h2, vc.w)};

        #pragma unroll
        for (int t = 0; t < 4; ++t) {
            AF af;
            #pragma unroll
            for (int j = 0; j < 4; ++j) {
                h2 d = cc[j] + aak[t];
                d = __builtin_elementwise_fma(pxk[t], cx[j], d);
                d = __builtin_elementwise_fma(pyk[t], cy[j], d);
                d = __builtin_elementwise_fma(pzk[t], cz[j], d);
                af.h[j] = pk_sqrt_fast(d, mhf, c15);
            }
            acc[t][0] = __builtin_amdgcn_mfma_f32_16x16x32_f16(af.v, wf0.v, acc[t][0], 0, 0, 0);
            acc[t][1] = __builtin_amdgcn_mfma_f32_16x16x32_f16(af.v, wf1.v, acc[t][1], 0, 0, 0);
            acc[t][2] = __builtin_amdgcn_mfma_f32_16x16x32_f16(af.v, wf2.v, acc[t][2], 0, 0, 0);
            acc[t][3] = __builtin_amdgcn_mfma_f32_16x16x32_f16(af.v, wf3.v, acc[t][3], 0, 0, 0);
        }
    }

    // ---- two-phase cross-chunk reduction through LDS (f16 partials, 8 slots) ----
    // acc[t][kt][reg] = partial out[rowbase + t*16 + g*4 + reg][kt*16 + m] for chunk wv
    {
        _Float16* base = sR + (wv & 7) * 4096;
        if (wv < 8) {
            #pragma unroll
            for (int t = 0; t < 4; ++t)
                #pragma unroll
                for (int kt = 0; kt < 4; ++kt)
                    #pragma unroll
                    for (int reg = 0; reg < 4; ++reg)
                        base[(t * 16 + g * 4 + reg) * 64 + kt * 16 + m] =
                            (_Float16)acc[t][kt][reg];
        }
        __syncthreads();
        if (wv >= 8) {
            #pragma unroll
            for (int t = 0; t < 4; ++t)
                #pragma unroll
                for (int kt = 0; kt < 4; ++kt)
                    #pragma unroll
                    for (int reg = 0; reg < 4; ++reg) {
                        const int idx = (t * 16 + g * 4 + reg) * 64 + kt * 16 + m;
                        base[idx] = (_Float16)((float)base[idx] + acc[t][kt][reg]);
                    }
        }
        __syncthreads();
    }

    // final: 1024 threads -> (row = tid>>4 in [0,64), kq = tid&15); sum 8 slots, store
    {
        const int row = tid >> 4;
        const int kq  = tid & 15;
        const _Float16* p = sR + row * 64 + kq * 4;
        float4 s0 = make_float4(0.f, 0.f, 0.f, 0.f);
        #pragma unroll
        for (int w = 0; w < 8; ++w) {
            const uint2 pv = *(const uint2*)(p + w * 4096);
            const h2 lo = __builtin_bit_cast(h2, pv.x);
            const h2 hi = __builtin_bit_cast(h2, pv.y);
            s0.x += (float)lo[0]; s0.y += (float)lo[1];
            s0.z += (float)hi[0]; s0.w += (float)hi[1];
        }
        *(float4*)(out + (rowbase + row) * K_OUT + kq * 4) = s0;
    }
}

extern "C" void kernel_launch(void* const* d_in, const int* in_sizes, int n_in,
                              void* d_out, int out_size, void* d_ws, size_t ws_size,
                              hipStream_t stream) {
    (void)in_sizes; (void)n_in; (void)out_size; (void)ws_size;
    const float* Xp  = (const float*)d_in[0];   // (16384,3)
    const float* X   = (const float*)d_in[1];   // (8192,3)
    const float* Wf  = (const float*)d_in[2];   // (64,8192)
    const float* eps = (const float*)d_in[3];   // scalar
    float* out = (float*)d_out;                 // (16384,64)

    // ws: Wt (fragment-linear f16 W) 1 MiB | Cx,Cy,Cz,Cc 16 KiB each
    uint4*    Wt = (uint4*)d_ws;
    uint32_t* Cx = (uint32_t*)((char*)d_ws + (1u << 20));
    uint32_t* Cy = Cx + 4096;
    uint32_t* Cz = Cy + 4096;
    uint32_t* Cc = Cz + 4096;

    rbf_prep<<<dim3(272), dim3(256), 0, stream>>>(Wf, X, eps, Wt, Cx, Cy, Cz, Cc);
    rbf_main<<<dim3(M_ROWS / 64), dim3(1024), 0, stream>>>(
        Xp, Wt, Cx, Cy, Cz, Cc, eps, out);
}

// Round 11
// 107.797 us; speedup vs baseline: 1.5349x; 1.5349x over previous
//
#include <hip/hip_runtime.h>
#include <hip/hip_fp16.h>
#include <stdint.h>

// Problem constants: Xp(16384,3) X(8192,3) W(64,8192) eps scalar -> out(16384,64)
#define M_ROWS 16384
#define N_PTS  8192
#define K_OUT  64

typedef _Float16       h2     __attribute__((ext_vector_type(2)));
typedef unsigned short u16x2  __attribute__((ext_vector_type(2)));
typedef _Float16       f16x8  __attribute__((ext_vector_type(8)));
typedef float          f32x16 __attribute__((ext_vector_type(16)));

union AF { f16x8 v; uint4 q; uint32_t u[4]; h2 h[4]; };

__device__ __forceinline__ h2 pkrtz2(float a, float b) {
    return __builtin_bit_cast(h2, __builtin_amdgcn_cvt_pkrtz(a, b));
}
__device__ __forceinline__ uint32_t pkrtz(float a, float b) {
    return __builtin_bit_cast(uint32_t, __builtin_amdgcn_cvt_pkrtz(a, b));
}

// packed fast sqrt(t), t in [1, ~512]: per-half rsqrt bit-seed + 1 reassociated
// Newton. Rel err <= ~3e-3 (validated r5-r10, absmax 8).
__device__ __forceinline__ h2 pk_sqrt_fast(h2 t, h2 mhf, h2 c15) {
    u16x2 u = __builtin_bit_cast(u16x2, t);
    u16x2 r0u = (u16x2){0x59BA, 0x59BA} - (u >> 1);
    h2 r0 = __builtin_bit_cast(h2, r0u);
    h2 y = t * r0;
    h2 p = y * r0;
    h2 k = __builtin_elementwise_fma(p, mhf, c15);
    return y * k;
}

// ---------------- prep ----------------
// blocks [0,256): W -> 32x32x16 B-frag-linear f16 Wt.
//   global thread t in [0,65536): lane=t&63, ct=(t>>6)&1, b=t>>7 (16-pt group).
//   Wt[(b*2+ct)*64+lane] = f16 W[ct*32+(lane&31)][b*16+(lane>>5)*8 + j], j=0..7.
// blocks [256,272): coord streams as packed-f16 pairs (4096 dwords each):
//   Cx = -2*eps*x, Cy, Cz, Cc = |eps*x|^2 + 1   (unchanged since r7)
__global__ __launch_bounds__(256) void rbf_prep(
    const float* __restrict__ Wf, const float* __restrict__ X,
    const float* __restrict__ epsp,
    uint4* __restrict__ Wt, uint32_t* __restrict__ Cx,
    uint32_t* __restrict__ Cy, uint32_t* __restrict__ Cz,
    uint32_t* __restrict__ Cc)
{
    const int bid = blockIdx.x, tid = threadIdx.x;
    if (bid < 256) {
        const int t    = bid * 256 + tid;     // [0, 65536)
        const int lane = t & 63;
        const int ct   = (t >> 6) & 1;
        const int b    = t >> 7;              // [0, 512) 16-pt groups
        const int row  = ct * 32 + (lane & 31);
        const int colb = b * 16 + (lane >> 5) * 8;
        const float4* src = (const float4*)(Wf + row * N_PTS + colb);
        const float4 w0 = src[0], w1 = src[1];
        uint4 p;
        p.x = pkrtz(w0.x, w0.y);
        p.y = pkrtz(w0.z, w0.w);
        p.z = pkrtz(w1.x, w1.y);
        p.w = pkrtz(w1.z, w1.w);
        Wt[(b * 2 + ct) * 64 + lane] = p;
    } else {
        const int n = (bid - 256) * 256 + tid;       // pair index [0, 4096)
        const float e = *epsp;
        const float2 A = *(const float2*)(X + 6 * n);      // x0 y0
        const float2 B = *(const float2*)(X + 6 * n + 2);  // z0 x1
        const float2 C = *(const float2*)(X + 6 * n + 4);  // y1 z1
        const float x0 = A.x * e, y0 = A.y * e, z0 = B.x * e;
        const float x1 = B.y * e, y1 = C.x * e, z1 = C.y * e;
        Cx[n] = pkrtz(-2.0f * x0, -2.0f * x1);
        Cy[n] = pkrtz(-2.0f * y0, -2.0f * y1);
        Cz[n] = pkrtz(-2.0f * z0, -2.0f * z1);
        Cc[n] = pkrtz(fmaf(x0, x0, fmaf(y0, y0, fmaf(z0, z0, 1.0f))),
                      fmaf(x1, x1, fmaf(y1, y1, fmaf(z1, z1, 1.0f))));
    }
}

// ---------------- main: 32x32x16 MFMA, 2x2 frags = 64x64 tile/wave ----------------
// 256 blocks x 1024 threads (1 block/CU, 4 waves/SIMD, 128 unified regs/wave).
// Block owns rows [bid*64, +64); wave wv = n-chunk covers pts [wv*512, +512)
// = 32 iters of 16 pts, 4 MFMA each. Demand ~114 unified regs <= 128 (r10 lesson:
// the 16x16 T=4 shape needs ~134 -> spill; 32x32 halves W/coord/geom state).
// A layout (assumed, mirrors verified 16x16): m=lane&31, k=(lane>>5)*8+j.
// C/D layout (measured m74/m101): col=lane&31, row=(reg&3)+8*(reg>>2)+4*(lane>>5).
__global__ __launch_bounds__(1024, 4) void rbf_main(
    const float* __restrict__ Xp, const uint4* __restrict__ Wt,
    const uint32_t* __restrict__ Cx, const uint32_t* __restrict__ Cy,
    const uint32_t* __restrict__ Cz, const uint32_t* __restrict__ Cc,
    const float* __restrict__ epsp, float* __restrict__ out)
{
    __shared__ __align__(16) _Float16 sR[8 * 64 * 64];   // 64 KB: [slot][row(64)][col(64)]

    const int tid  = threadIdx.x;
    const int lane = tid & 63;
    const int wv   = tid >> 6;        // n-chunk 0..15
    const int col  = lane & 31;
    const int g8   = lane >> 5;

    const int rowbase = blockIdx.x * 64;

    // per-lane row geometry for 2 row-tiles (rows rowbase + tt*32 + col)
    const float e = *epsp;
    h2 pxk[2], pyk[2], pzk[2], aak[2];
    #pragma unroll
    for (int tt = 0; tt < 2; ++tt) {
        const int r = rowbase + tt * 32 + col;
        const float px = Xp[3 * r + 0] * e;
        const float py = Xp[3 * r + 1] * e;
        const float pz = Xp[3 * r + 2] * e;
        const float a  = fmaf(px, px, fmaf(py, py, pz * pz));
        pxk[tt] = pkrtz2(px, px);
        pyk[tt] = pkrtz2(py, py);
        pzk[tt] = pkrtz2(pz, pz);
        aak[tt] = pkrtz2(a, a);
    }
    const h2 mhf = {(_Float16)-0.5f, (_Float16)-0.5f};
    const h2 c15 = {(_Float16)1.5f, (_Float16)1.5f};

    f32x16 acc[2][2];
    #pragma unroll
    for (int tt = 0; tt < 2; ++tt)
        #pragma unroll
        for (int ct = 0; ct < 2; ++ct)
            acc[tt][ct] = (f32x16)(0.f);

    // uniform bases; divergent part is a FIXED lane offset.
    // coords: lane-group g8 needs pts s*16+g8*8..+8 = dwords wv*256 + s*8 + g8*4
    const uint32_t* cxp = Cx + wv * 256 + g8 * 4;
    const uint32_t* cyp = Cy + wv * 256 + g8 * 4;
    const uint32_t* czp = Cz + wv * 256 + g8 * 4;
    const uint32_t* ccp = Cc + wv * 256 + g8 * 4;
    // W: group b = wv*32 + s; uint4 idx (b*2+ct)*64 + lane
    const uint4* wp = Wt + wv * 32 * 128 + lane;

    #pragma unroll 4
    for (int s = 0; s < 32; ++s) {
        const uint4 vx = *(const uint4*)(cxp + s * 8);
        const uint4 vy = *(const uint4*)(cyp + s * 8);
        const uint4 vz = *(const uint4*)(czp + s * 8);
        const uint4 vc = *(const uint4*)(ccp + s * 8);

        AF w0, w1;
        w0.q = wp[s * 128];
        w1.q = wp[s * 128 + 64];

        const h2 cx[4] = {__builtin_bit_cast(h2, vx.x), __builtin_bit_cast(h2, vx.y),
                          __builtin_bit_cast(h2, vx.z), __builtin_bit_cast(h2, vx.w)};
        const h2 cy[4] = {__builtin_bit_cast(h2, vy.x), __builtin_bit_cast(h2, vy.y),
                          __builtin_bit_cast(h2, vy.z), __builtin_bit_cast(h2, vy.w)};
        const h2 cz[4] = {__builtin_bit_cast(h2, vz.x), __builtin_bit_cast(h2, vz.y),
                          __builtin_bit_cast(h2, vz.z), __builtin_bit_cast(h2, vz.w)};
        const h2 cc[4] = {__builtin_bit_cast(h2, vc.x), __builtin_bit_cast(h2, vc.y),
                          __builtin_bit_cast(h2, vc.z), __builtin_bit_cast(h2, vc.w)};

        #pragma unroll
        for (int tt = 0; tt < 2; ++tt) {
            AF af;
            #pragma unroll
            for (int j = 0; j < 4; ++j) {
                h2 d = cc[j] + aak[tt];
                d = __builtin_elementwise_fma(pxk[tt], cx[j], d);
                d = __builtin_elementwise_fma(pyk[tt], cy[j], d);
                d = __builtin_elementwise_fma(pzk[tt], cz[j], d);
                af.h[j] = pk_sqrt_fast(d, mhf, c15);
            }
            acc[tt][0] = __builtin_amdgcn_mfma_f32_32x32x16_f16(af.v, w0.v, acc[tt][0], 0, 0, 0);
            acc[tt][1] = __builtin_amdgcn_mfma_f32_32x32x16_f16(af.v, w1.v, acc[tt][1], 0, 0, 0);
        }
    }

    // ---- two-phase cross-chunk reduction through LDS (f16 partials, 8 slots) ----
    // acc[tt][ct][reg] = partial out[rowbase + tt*32 + rowD][ct*32 + col],
    // rowD = (reg&3) + 8*(reg>>2) + 4*g8
    {
        _Float16* base = sR + (wv & 7) * 4096;
        if (wv < 8) {
            #pragma unroll
            for (int tt = 0; tt < 2; ++tt)
                #pragma unroll
                for (int ct = 0; ct < 2; ++ct)
                    #pragma unroll
                    for (int reg = 0; reg < 16; ++reg) {
                        const int rowD = (reg & 3) + 8 * (reg >> 2) + 4 * g8;
                        base[(tt * 32 + rowD) * 64 + ct * 32 + col] =
                            (_Float16)acc[tt][ct][reg];
                    }
        }
        __syncthreads();
        if (wv >= 8) {
            #pragma unroll
            for (int tt = 0; tt < 2; ++tt)
                #pragma unroll
                for (int ct = 0; ct < 2; ++ct)
                    #pragma unroll
                    for (int reg = 0; reg < 16; ++reg) {
                        const int rowD = (reg & 3) + 8 * (reg >> 2) + 4 * g8;
                        const int idx = (tt * 32 + rowD) * 64 + ct * 32 + col;
                        base[idx] = (_Float16)((float)base[idx] + acc[tt][ct][reg]);
                    }
        }
        __syncthreads();
    }

    // final: 1024 threads -> (row = tid>>4 in [0,64), kq = tid&15); sum 8 slots, store
    {
        const int row = tid >> 4;
        const int kq  = tid & 15;
        const _Float16* p = sR + row * 64 + kq * 4;
        float4 s0 = make_float4(0.f, 0.f, 0.f, 0.f);
        #pragma unroll
        for (int w = 0; w < 8; ++w) {
            const uint2 pv = *(const uint2*)(p + w * 4096);
            const h2 lo = __builtin_bit_cast(h2, pv.x);
            const h2 hi = __builtin_bit_cast(h2, pv.y);
            s0.x += (float)lo[0]; s0.y += (float)lo[1];
            s0.z += (float)hi[0]; s0.w += (float)hi[1];
        }
        *(float4*)(out + (rowbase + row) * K_OUT + kq * 4) = s0;
    }
}

extern "C" void kernel_launch(void* const* d_in, const int* in_sizes, int n_in,
                              void* d_out, int out_size, void* d_ws, size_t ws_size,
                              hipStream_t stream) {
    (void)in_sizes; (void)n_in; (void)out_size; (void)ws_size;
    const float* Xp  = (const float*)d_in[0];   // (16384,3)
    const float* X   = (const float*)d_in[1];   // (8192,3)
    const float* Wf  = (const float*)d_in[2];   // (64,8192)
    const float* eps = (const float*)d_in[3];   // scalar
    float* out = (float*)d_out;                 // (16384,64)

    // ws: Wt (32x32 B-frag-linear f16 W) 1 MiB | Cx,Cy,Cz,Cc 16 KiB each
    uint4*    Wt = (uint4*)d_ws;
    uint32_t* Cx = (uint32_t*)((char*)d_ws + (1u << 20));
    uint32_t* Cy = Cx + 4096;
    uint32_t* Cz = Cy + 4096;
    uint32_t* Cc = Cz + 4096;

    rbf_prep<<<dim3(272), dim3(256), 0, stream>>>(Wf, X, eps, Wt, Cx, Cy, Cz, Cc);
    rbf_main<<<dim3(M_ROWS / 64), dim3(1024), 0, stream>>>(
        Xp, Wt, Cx, Cy, Cz, Cc, eps, out);
}

// Round 12
// 96.733 us; speedup vs baseline: 1.7105x; 1.1144x over previous
//
#include <hip/hip_runtime.h>
#include <hip/hip_fp16.h>
#include <stdint.h>

// Problem constants: Xp(16384,3) X(8192,3) W(64,8192) eps scalar -> out(16384,64)
#define M_ROWS 16384
#define N_PTS  8192
#define K_OUT  64

typedef _Float16       h2     __attribute__((ext_vector_type(2)));
typedef unsigned short u16x2  __attribute__((ext_vector_type(2)));
typedef _Float16       f16x8  __attribute__((ext_vector_type(8)));
typedef float          f32x16 __attribute__((ext_vector_type(16)));

union AF { f16x8 v; uint4 q; uint32_t u[4]; h2 h[4]; };

__device__ __forceinline__ h2 pkrtz2(float a, float b) {
    return __builtin_bit_cast(h2, __builtin_amdgcn_cvt_pkrtz(a, b));
}
__device__ __forceinline__ uint32_t pkrtz(float a, float b) {
    return __builtin_bit_cast(uint32_t, __builtin_amdgcn_cvt_pkrtz(a, b));
}

// packed fast sqrt(t), t in [1, ~512]: per-half rsqrt bit-seed + 1 reassociated
// Newton. Rel err <= ~3e-3 (validated r5-r11, absmax 8).
__device__ __forceinline__ h2 pk_sqrt_fast(h2 t, h2 mhf, h2 c15) {
    u16x2 u = __builtin_bit_cast(u16x2, t);
    u16x2 r0u = (u16x2){0x59BA, 0x59BA} - (u >> 1);
    h2 r0 = __builtin_bit_cast(h2, r0u);
    h2 y = t * r0;
    h2 p = y * r0;
    h2 k = __builtin_elementwise_fma(p, mhf, c15);
    return y * k;
}

// ---------------- prep (unchanged from r11) ----------------
// blocks [0,256): W -> 32x32x16 B-frag-linear f16 Wt:
//   Wt[(b*2+ct)*64+lane] = f16 W[ct*32+(lane&31)][b*16+(lane>>5)*8 + j], j=0..7
// blocks [256,272): coord streams as packed-f16 pairs (4096 dwords each,
//   CONTIGUOUS in ws: Cx|Cy|Cz|Cc): Cx=-2ex, Cy, Cz, Cc=|ex|^2+1
__global__ __launch_bounds__(256) void rbf_prep(
    const float* __restrict__ Wf, const float* __restrict__ X,
    const float* __restrict__ epsp,
    uint4* __restrict__ Wt, uint32_t* __restrict__ Cx,
    uint32_t* __restrict__ Cy, uint32_t* __restrict__ Cz,
    uint32_t* __restrict__ Cc)
{
    const int bid = blockIdx.x, tid = threadIdx.x;
    if (bid < 256) {
        const int t    = bid * 256 + tid;     // [0, 65536)
        const int lane = t & 63;
        const int ct   = (t >> 6) & 1;
        const int b    = t >> 7;              // [0, 512) 16-pt groups
        const int row  = ct * 32 + (lane & 31);
        const int colb = b * 16 + (lane >> 5) * 8;
        const float4* src = (const float4*)(Wf + row * N_PTS + colb);
        const float4 w0 = src[0], w1 = src[1];
        uint4 p;
        p.x = pkrtz(w0.x, w0.y);
        p.y = pkrtz(w0.z, w0.w);
        p.z = pkrtz(w1.x, w1.y);
        p.w = pkrtz(w1.z, w1.w);
        Wt[(b * 2 + ct) * 64 + lane] = p;
    } else {
        const int n = (bid - 256) * 256 + tid;       // pair index [0, 4096)
        const float e = *epsp;
        const float2 A = *(const float2*)(X + 6 * n);      // x0 y0
        const float2 B = *(const float2*)(X + 6 * n + 2);  // z0 x1
        const float2 C = *(const float2*)(X + 6 * n + 4);  // y1 z1
        const float x0 = A.x * e, y0 = A.y * e, z0 = B.x * e;
        const float x1 = B.y * e, y1 = C.x * e, z1 = C.y * e;
        Cx[n] = pkrtz(-2.0f * x0, -2.0f * x1);
        Cy[n] = pkrtz(-2.0f * y0, -2.0f * y1);
        Cz[n] = pkrtz(-2.0f * z0, -2.0f * z1);
        Cc[n] = pkrtz(fmaf(x0, x0, fmaf(y0, y0, fmaf(z0, z0, 1.0f))),
                      fmaf(x1, x1, fmaf(y1, y1, fmaf(z1, z1, 1.0f))));
    }
}

// ---------------- main: r11 structure + coords staged in LDS ----------------
// 256 blocks x 1024 threads (1 block/CU, 4 waves/SIMD at 128 unified regs).
// Change vs r11 (single variable): the 4 coord loads/iter become ds_read
// broadcasts from a 64 KB LDS image staged once at block start; only the 2
// W loads/iter remain on the vmcnt queue (r11 post-mortem: ~160 cyc exposed
// per global load at 4-reg slack -> coords were 2/3 of the exposure).
// The reduction buffer REUSES the same 64 KB after a barrier.
__global__ __launch_bounds__(1024, 4) void rbf_main(
    const float* __restrict__ Xp, const uint4* __restrict__ Wt,
    const uint32_t* __restrict__ Cx, const float* __restrict__ epsp,
    float* __restrict__ out)
{
    __shared__ __align__(16) uint4 sC4[4096];   // 64 KB: coords, then f16 partials

    const int tid  = threadIdx.x;
    const int lane = tid & 63;
    const int wv   = tid >> 6;        // n-chunk 0..15
    const int col  = lane & 31;
    const int g8   = lane >> 5;

    const int rowbase = blockIdx.x * 64;

    // ---- stage all coord streams into LDS (64 KB, coalesced) ----
    {
        const uint4* g = (const uint4*)Cx;   // Cx|Cy|Cz|Cc contiguous = 4096 uint4
        #pragma unroll
        for (int k = 0; k < 4; ++k)
            sC4[tid + k * 1024] = g[tid + k * 1024];
    }

    // per-lane row geometry for 2 row-tiles (rows rowbase + tt*32 + col)
    const float e = *epsp;
    h2 pxk[2], pyk[2], pzk[2], aak[2];
    #pragma unroll
    for (int tt = 0; tt < 2; ++tt) {
        const int r = rowbase + tt * 32 + col;
        const float px = Xp[3 * r + 0] * e;
        const float py = Xp[3 * r + 1] * e;
        const float pz = Xp[3 * r + 2] * e;
        const float a  = fmaf(px, px, fmaf(py, py, pz * pz));
        pxk[tt] = pkrtz2(px, px);
        pyk[tt] = pkrtz2(py, py);
        pzk[tt] = pkrtz2(pz, pz);
        aak[tt] = pkrtz2(a, a);
    }
    const h2 mhf = {(_Float16)-0.5f, (_Float16)-0.5f};
    const h2 c15 = {(_Float16)1.5f, (_Float16)1.5f};

    f32x16 acc[2][2];
    #pragma unroll
    for (int tt = 0; tt < 2; ++tt)
        #pragma unroll
        for (int ct = 0; ct < 2; ++ct)
            acc[tt][ct] = (f32x16)(0.f);

    __syncthreads();   // coords visible

    // W: group b = wv*32 + s; uint4 idx (b*2+ct)*64 + lane (fragment-linear)
    const uint4* wp = Wt + wv * 32 * 128 + lane;
    // coords in LDS: uint4 idx = stream*1024 + wv*64 + s*2 + g8 (32-lane broadcast)
    const int cbase = wv * 64 + g8;

    #pragma unroll 4
    for (int s = 0; s < 32; ++s) {
        const uint4 vx = sC4[cbase + s * 2];
        const uint4 vy = sC4[cbase + s * 2 + 1024];
        const uint4 vz = sC4[cbase + s * 2 + 2048];
        const uint4 vc = sC4[cbase + s * 2 + 3072];

        AF w0, w1;
        w0.q = wp[s * 128];
        w1.q = wp[s * 128 + 64];

        const h2 cx[4] = {__builtin_bit_cast(h2, vx.x), __builtin_bit_cast(h2, vx.y),
                          __builtin_bit_cast(h2, vx.z), __builtin_bit_cast(h2, vx.w)};
        const h2 cy[4] = {__builtin_bit_cast(h2, vy.x), __builtin_bit_cast(h2, vy.y),
                          __builtin_bit_cast(h2, vy.z), __builtin_bit_cast(h2, vy.w)};
        const h2 cz[4] = {__builtin_bit_cast(h2, vz.x), __builtin_bit_cast(h2, vz.y),
                          __builtin_bit_cast(h2, vz.z), __builtin_bit_cast(h2, vz.w)};
        const h2 cc[4] = {__builtin_bit_cast(h2, vc.x), __builtin_bit_cast(h2, vc.y),
                          __builtin_bit_cast(h2, vc.z), __builtin_bit_cast(h2, vc.w)};

        #pragma unroll
        for (int tt = 0; tt < 2; ++tt) {
            AF af;
            #pragma unroll
            for (int j = 0; j < 4; ++j) {
                h2 d = cc[j] + aak[tt];
                d = __builtin_elementwise_fma(pxk[tt], cx[j], d);
                d = __builtin_elementwise_fma(pyk[tt], cy[j], d);
                d = __builtin_elementwise_fma(pzk[tt], cz[j], d);
                af.h[j] = pk_sqrt_fast(d, mhf, c15);
            }
            acc[tt][0] = __builtin_amdgcn_mfma_f32_32x32x16_f16(af.v, w0.v, acc[tt][0], 0, 0, 0);
            acc[tt][1] = __builtin_amdgcn_mfma_f32_32x32x16_f16(af.v, w1.v, acc[tt][1], 0, 0, 0);
        }
    }

    __syncthreads();   // all waves done with coords; reuse LDS for partials

    // ---- two-phase cross-chunk reduction (f16 partials, 8 slots over sC4) ----
    // acc[tt][ct][reg] = partial out[rowbase + tt*32 + rowD][ct*32 + col],
    // rowD = (reg&3) + 8*(reg>>2) + 4*g8   (verified r11)
    _Float16* sR = (_Float16*)sC4;
    {
        _Float16* base = sR + (wv & 7) * 4096;
        if (wv < 8) {
            #pragma unroll
            for (int tt = 0; tt < 2; ++tt)
                #pragma unroll
                for (int ct = 0; ct < 2; ++ct)
                    #pragma unroll
                    for (int reg = 0; reg < 16; ++reg) {
                        const int rowD = (reg & 3) + 8 * (reg >> 2) + 4 * g8;
                        base[(tt * 32 + rowD) * 64 + ct * 32 + col] =
                            (_Float16)acc[tt][ct][reg];
                    }
        }
        __syncthreads();
        if (wv >= 8) {
            #pragma unroll
            for (int tt = 0; tt < 2; ++tt)
                #pragma unroll
                for (int ct = 0; ct < 2; ++ct)
                    #pragma unroll
                    for (int reg = 0; reg < 16; ++reg) {
                        const int rowD = (reg & 3) + 8 * (reg >> 2) + 4 * g8;
                        const int idx = (tt * 32 + rowD) * 64 + ct * 32 + col;
                        base[idx] = (_Float16)((float)base[idx] + acc[tt][ct][reg]);
                    }
        }
        __syncthreads();
    }

    // final: 1024 threads -> (row = tid>>4 in [0,64), kq = tid&15); sum 8 slots, store
    {
        const int row = tid >> 4;
        const int kq  = tid & 15;
        const _Float16* p = sR + row * 64 + kq * 4;
        float4 s0 = make_float4(0.f, 0.f, 0.f, 0.f);
        #pragma unroll
        for (int w = 0; w < 8; ++w) {
            const uint2 pv = *(const uint2*)(p + w * 4096);
            const h2 lo = __builtin_bit_cast(h2, pv.x);
            const h2 hi = __builtin_bit_cast(h2, pv.y);
            s0.x += (float)lo[0]; s0.y += (float)lo[1];
            s0.z += (float)hi[0]; s0.w += (float)hi[1];
        }
        *(float4*)(out + (rowbase + row) * K_OUT + kq * 4) = s0;
    }
}

extern "C" void kernel_launch(void* const* d_in, const int* in_sizes, int n_in,
                              void* d_out, int out_size, void* d_ws, size_t ws_size,
                              hipStream_t stream) {
    (void)in_sizes; (void)n_in; (void)out_size; (void)ws_size;
    const float* Xp  = (const float*)d_in[0];   // (16384,3)
    const float* X   = (const float*)d_in[1];   // (8192,3)
    const float* Wf  = (const float*)d_in[2];   // (64,8192)
    const float* eps = (const float*)d_in[3];   // scalar
    float* out = (float*)d_out;                 // (16384,64)

    // ws: Wt (32x32 B-frag-linear f16 W) 1 MiB | Cx,Cy,Cz,Cc contiguous 16 KiB each
    uint4*    Wt = (uint4*)d_ws;
    uint32_t* Cx = (uint32_t*)((char*)d_ws + (1u << 20));
    uint32_t* Cy = Cx + 4096;
    uint32_t* Cz = Cy + 4096;
    uint32_t* Cc = Cz + 4096;

    rbf_prep<<<dim3(272), dim3(256), 0, stream>>>(Wf, X, eps, Wt, Cx, Cy, Cz, Cc);
    rbf_main<<<dim3(M_ROWS / 64), dim3(1024), 0, stream>>>(Xp, Wt, Cx, eps, out);
}